// Round 13
// baseline (376.177 us; speedup 1.0000x reference)
//
#include <hip/hip_runtime.h>

// ---------------------------------------------------------------------------
// AxialBlock fused implementation. Round 13: packed upper-tri tables in
// k_att_stats (22.5KB LDS -> 7 blocks/CU); k_att2 phase-A kt pair-loads +
// dual accumulation chains; merged pre-kernel (cvt+rel prep).
// NB=16, CIN=128, COUT=256, MID=128, G=8, GP=16, K=64
// ---------------------------------------------------------------------------

#define NCOPY 64

typedef __attribute__((ext_vector_type(8))) short bf16x8;
typedef __attribute__((ext_vector_type(4))) short bf16x4;
typedef __attribute__((ext_vector_type(4))) float f32x4;
typedef __attribute__((ext_vector_type(2))) float f32x2;

__device__ __forceinline__ float wave_sum(float v){
  #pragma unroll
  for (int o = 32; o; o >>= 1) v += __shfl_xor(v, o, 64);
  return v;
}
__device__ __forceinline__ ushort f2bf(float f){
  union { float f; unsigned u; } v; v.f = f;
  unsigned r = v.u + 0x7FFFu + ((v.u >> 16) & 1u);   // round-to-nearest-even
  return (ushort)(r >> 16);
}
__device__ __forceinline__ float bf2f(ushort u){
  union { unsigned u; float f; } v; v.u = ((unsigned)u) << 16;
  return v.f;
}

// ---------------------------------------------------------------------------
// merged pre-pass: blocks 0..575 = weight fp32->bf16; 576..579 = rel
// windowed sums/correlations (PACKED upper-triangle: 36 pairs).
// ---------------------------------------------------------------------------
__global__ void k_pre(const float* __restrict__ s0, const float* __restrict__ s1,
                      const float* __restrict__ s2, const float* __restrict__ s3,
                      const float* __restrict__ s4, ushort* __restrict__ dst,
                      const float* __restrict__ relh, const float* __restrict__ relw,
                      float* __restrict__ rwh, float* __restrict__ rww){
  const int blk = blockIdx.x;
  if (blk < 576){
    int i = blk*256 + threadIdx.x;
    if (i >= 147456) return;
    float v;
    if      (i < 16384)  v = s0[i];
    else if (i < 49152)  v = s1[i-16384];
    else if (i < 81920)  v = s2[i-49152];
    else if (i < 114688) v = s3[i-81920];
    else                 v = s4[i-114688];
    dst[i] = f2bf(v);
  } else {
    const int sidx = blk - 576;
    const float* rel = (sidx & 2) ? relw : relh;
    float* rw        = (sidx & 2) ? rww  : rwh;
    const int side = sidx & 1;
    const float* base = rel + side*8*127;
    float* Wout = rw + side*2304;
    float* Sout = rw + 4608 + side*512;
    const int tid = threadIdx.x;
    for (int idx = tid; idx < 2304; idx += 256){
      int pr = idx >> 6, i = idx & 63;
      int c = 0, off = pr;
      #pragma unroll
      for (int cc = 0; cc < 7; ++cc){ if (off >= 8 - c){ off -= (8 - c); ++c; } }
      int c2 = c + off;
      const float* r1 = base + c*127 + i;
      const float* r2 = base + c2*127 + i;
      float s = 0.f;
      #pragma unroll 8
      for (int u = 0; u < 64; ++u) s = fmaf(r1[u], r2[u], s);
      Wout[idx] = s;
    }
    for (int idx = tid; idx < 512; idx += 256){
      int c = idx >> 6, i = idx & 63;
      const float* r1 = base + c*127 + i;
      float s = 0.f;
      #pragma unroll 8
      for (int u = 0; u < 64; ++u) s += r1[u];
      Sout[idx] = s;
    }
  }
}

// ---------------------------------------------------------------------------
// MFMA GEMM: out[o][col] = sum_c Wb[o][c] * X[c][col]  (+ epilogue per MODE)
// MODE 0: + bias, write, stats.  MODE 1: write, stats.  MODE 2: + bias +
// scsh*y2(bf16) residual, write, no stats.  MODE 3: qkv split write
// (even 16-row subtiles = q/k fp32 -> out_; odd = v bf16 -> vout) + stats.
// ---------------------------------------------------------------------------
template<int O, int MODE, int SLOG, int INBF, int OUTBF>
__global__ __launch_bounds__(256) void k_gemm(
    const void* __restrict__ X_, const ushort* __restrict__ Wb,
    const float* __restrict__ bias, void* __restrict__ out_,
    float* __restrict__ acc, const ushort* __restrict__ y2,
    const float* __restrict__ scsh, ushort* __restrict__ vout)
{
  constexpr int RPW = O/4;       // rows per wave
  constexpr int NS  = RPW/16;    // 16-row subtiles per wave
  __shared__ ushort XT[64*128];  // [col][k] bf16, chunk-XOR swizzled

  const int tid = threadIdx.x;
  const int col0 = blockIdx.x << 6;
  const int seg  = col0 >> SLOG;
  const int p0   = col0 & ((1<<SLOG)-1);

  // ---- stage X tile (128c x 64col) -> bf16 transposed+swizzled ----
  {
    const int col = tid & 63;
    const int kc8 = tid >> 6;                  // 0..3
    #pragma unroll
    for (int q = 0; q < 4; ++q){
      int kc = kc8*4 + q;                      // k-chunk 0..15 (8 c's each)
      int c0 = kc*8;
      bf16x8 pk;
      if constexpr (INBF){
        const ushort* xb = (const ushort*)X_ + (((size_t)seg*128) << SLOG) + p0 + col;
        #pragma unroll
        for (int j = 0; j < 8; ++j)
          pk[j] = (short)xb[(size_t)(c0+j) << SLOG];
      } else {
        const float* xb = (const float*)X_ + (((size_t)seg*128) << SLOG) + p0 + col;
        #pragma unroll
        for (int j = 0; j < 8; ++j)
          pk[j] = (short)f2bf(xb[(size_t)(c0+j) << SLOG]);
      }
      *(bf16x8*)&XT[col*128 + ((kc ^ (col & 15)) << 3)] = pk;
    }
  }
  __syncthreads();

  const int lane = tid & 63;
  const int wid  = tid >> 6;
  const int l15  = lane & 15, lg = lane >> 4;

  f32x4 accr[NS][4];
  #pragma unroll
  for (int s = 0; s < NS; ++s)
    #pragma unroll
    for (int ns = 0; ns < 4; ++ns)
      accr[s][ns] = (f32x4){0.f,0.f,0.f,0.f};

  #pragma unroll
  for (int kk = 0; kk < 4; ++kk){
    bf16x8 af[NS];
    #pragma unroll
    for (int s = 0; s < NS; ++s){
      int m = wid*RPW + s*16 + l15;
      af[s] = *(const bf16x8*)(Wb + (size_t)m*128 + kk*32 + lg*8);
    }
    bf16x8 bfr[4];
    #pragma unroll
    for (int ns = 0; ns < 4; ++ns){
      int ncol  = ns*16 + l15;
      int chunk = kk*4 + lg;
      bfr[ns] = *(const bf16x8*)&XT[ncol*128 + ((chunk ^ l15) << 3)];
    }
    #pragma unroll
    for (int s = 0; s < NS; ++s)
      #pragma unroll
      for (int ns = 0; ns < 4; ++ns)
        accr[s][ns] = __builtin_amdgcn_mfma_f32_16x16x32_bf16(
                        af[s], bfr[ns], accr[s][ns], 0, 0, 0);
  }

  // ---- epilogue ----
  float* accb = (MODE != 2) ? acc + (size_t)(blockIdx.x & (NCOPY-1))*2*O : nullptr;
  #pragma unroll
  for (int s = 0; s < NS; ++s){
    #pragma unroll
    for (int r = 0; r < 4; ++r){
      const int m = wid*RPW + s*16 + lg*4 + r;
      const float bs = (MODE == 0 || MODE == 2) ? bias[m] : 0.f;
      float vsum = 0.f, vsq = 0.f;
      #pragma unroll
      for (int ns = 0; ns < 4; ++ns){
        float v = accr[s][ns][r] + bs;
        if constexpr (MODE == 3){
          const int cm = ((m >> 5) << 4) + (m & 15);
          size_t oidx = (((size_t)seg*128 + cm) << SLOG) + p0 + ns*16 + l15;
          if ((s & 1) == 0) ((float*)out_)[oidx] = v;    // q,k fp32
          else              vout[oidx] = f2bf(v);        // v bf16
        } else {
          size_t oidx = (((size_t)seg*O + m) << SLOG) + p0 + ns*16 + l15;
          if (MODE == 2)
            v += fmaf(scsh[m], bf2f(y2[oidx]), scsh[O+m]);
          if constexpr (OUTBF) ((ushort*)out_)[oidx] = f2bf(v);
          else                 ((float*) out_)[oidx] = v;
        }
        vsum += v; vsq = fmaf(v, v, vsq);
      }
      if (MODE != 2){
        #pragma unroll
        for (int o2 = 1; o2 < 16; o2 <<= 1){
          vsum += __shfl_xor(vsum, o2, 64);
          vsq  += __shfl_xor(vsq , o2, 64);
        }
        if (l15 == 0){
          atomicAdd(&accb[m],   vsum);
          atomicAdd(&accb[O+m], vsq);
        }
      }
    }
  }
}

// ---------------------------------------------------------------------------
// BN finalize: sum NCOPY copies; scsh[c]=g*rstd ; scsh[C+c]=b-mean*scale
// ---------------------------------------------------------------------------
__global__ void k_finalize(const float* __restrict__ acc, const float* __restrict__ g,
    const float* __restrict__ b, float* __restrict__ scsh, int C, float invcnt)
{
  int c = blockIdx.x*blockDim.x + threadIdx.x;
  if (c >= C) return;
  float s = 0.f, s2 = 0.f;
  #pragma unroll 4
  for (int k2 = 0; k2 < NCOPY; ++k2){
    s  += acc[(size_t)k2*2*C + c];
    s2 += acc[(size_t)k2*2*C + C + c];
  }
  float mean = s*invcnt;
  float var  = s2*invcnt - mean*mean;
  float sc = g[c]*rsqrtf(var + 1e-5f);
  scsh[c]   = sc;
  scsh[C+c] = fmaf(-mean, sc, b[c]);
}

// ---------------------------------------------------------------------------
// bn1+relu + transpose (uint-vectorized)
// ---------------------------------------------------------------------------
__global__ __launch_bounds__(256) void k_trans_bnrelu(const ushort* __restrict__ out0,
    const float* __restrict__ scsh, ushort* __restrict__ hin)
{
  __shared__ float t[64][66];
  const int c = blockIdx.x, n = blockIdx.y;
  const int tid = threadIdx.x;
  const float sc = scsh[c], sh = scsh[128+c];
  const uint* src = (const uint*)(out0 + ((size_t)n*128 + c)*4096);
  #pragma unroll
  for (int r = 0; r < 8; ++r){
    int u = tid + r*256;
    uint a = src[u];
    f32x2 vv; vv.x = bf2f((ushort)a); vv.y = bf2f((ushort)(a >> 16));
    *(f32x2*)&t[u >> 5][(u & 31)*2] = vv;
  }
  __syncthreads();
  uint* dst = (uint*)(hin + (size_t)(n*64)*8192 + (size_t)c*64);
  #pragma unroll
  for (int r = 0; r < 8; ++r){
    int u = tid + r*256;
    int w = u >> 5, hp = u & 31;
    float v0 = fmaxf(fmaf(sc, t[2*hp    ][w], sh), 0.f);
    float v1 = fmaxf(fmaf(sc, t[2*hp + 1][w], sh), 0.f);
    dst[(size_t)w*4096 + hp] = ((uint)f2bf(v1) << 16) | f2bf(v0);
  }
}

// ---------------------------------------------------------------------------
// sim-BN stats per (b,g): Gram + rowsums via MFMA; PACKED upper-tri tables
// (22.5KB LDS -> 7 blocks/CU). grid (1024), block (64,4)
// ---------------------------------------------------------------------------
__global__ __launch_bounds__(256, 7) void k_att_stats(const float* __restrict__ qk32,
    const float* __restrict__ bq, const float* __restrict__ rw, float* __restrict__ accsim)
{
  __shared__ float WqS[2304], WkS[2304], SqS[512], SkS[512];
  const int b = blockIdx.x;
  const int tx = threadIdx.x, ty = threadIdx.y;
  const int tid = ty*64 + tx;
  for (int idx = tid; idx < 2304; idx += 256){ WqS[idx] = rw[idx]; WkS[idx] = rw[2304+idx]; }
  for (int idx = tid; idx < 512;  idx += 256){ SqS[idx] = rw[4608+idx]; SkS[idx] = rw[5120+idx]; }
  __syncthreads();
  float* accb = accsim + (size_t)(b & (NCOPY-1)) * 48;
  const int i = tx;
  const int l15 = tx & 15, lg = tx >> 4;
  const short one_bf = (short)0x3F80;
  const bf16x8 ones = {one_bf,one_bf,one_bf,one_bf,one_bf,one_bf,one_bf,one_bf};
  constexpr int tb[8] = {0,8,15,21,26,30,33,35};

  #pragma unroll
  for (int gi = 0; gi < 2; ++gi){
    const int g = ty*2 + gi;
    float q[8], k[8];
    #pragma unroll
    for (int c = 0; c < 8; ++c){
      int oq = g*32 + c, ok = oq + 8;
      q[c] = fmaf(bq[oq], qk32[((size_t)b*128 + g*16 + c    )*64 + i], bq[256+oq]);
      k[c] = fmaf(bq[ok], qk32[((size_t)b*128 + g*16 + 8 + c)*64 + i], bq[256+ok]);
    }
    const int och = g*32 + l15;
    const float gsc = bq[och], gsh = bq[256+och];
    const float* src = &qk32[((size_t)b*128 + g*16 + l15)*64 + lg*8];
    bf16x8 a0, a1;
    #pragma unroll
    for (int j = 0; j < 8; ++j) a0[j] = (short)f2bf(fmaf(gsc, src[j],      gsh));
    #pragma unroll
    for (int j = 0; j < 8; ++j) a1[j] = (short)f2bf(fmaf(gsc, src[32 + j], gsh));
    f32x4 G = (f32x4){0.f,0.f,0.f,0.f};
    f32x4 R = (f32x4){0.f,0.f,0.f,0.f};
    G = __builtin_amdgcn_mfma_f32_16x16x32_bf16(a0, a0, G, 0, 0, 0);
    G = __builtin_amdgcn_mfma_f32_16x16x32_bf16(a1, a1, G, 0, 0, 0);
    R = __builtin_amdgcn_mfma_f32_16x16x32_bf16(a0, ones, R, 0, 0, 0);
    R = __builtin_amdgcn_mfma_f32_16x16x32_bf16(a1, ones, R, 0, 0, 0);
    float ss = 0.f, sqk = 0.f;
    const bool gq_lane = (l15 < 8) && (lg < 2);
    const bool r_lane  = (l15 == 0) && (lg < 2);
    #pragma unroll
    for (int r = 0; r < 4; ++r){
      float gsw = __shfl_xor(G[r], 40, 64);
      float rsw = __shfl_xor(R[r], 32, 64);
      if (gq_lane) ss  = fmaf(G[r], gsw, ss);
      if (r_lane)  sqk = fmaf(R[r], rsw, sqk);
    }
    float aq = 0.f, ak = 0.f, aq2 = 0.f, ak2 = 0.f;
    #pragma unroll
    for (int c = 0; c < 8; ++c){
      aq = fmaf(q[c], SqS[c*64 + i], aq);
      ak = fmaf(k[c], SkS[c*64 + i], ak);
    }
    #pragma unroll
    for (int c = 0; c < 8; ++c){
      #pragma unroll
      for (int c2 = c; c2 < 8; ++c2){
        float w2 = (c2 == c) ? 1.f : 2.f;
        int pi = (tb[c] + c2 - c)*64 + i;
        aq2 = fmaf(w2*q[c]*q[c2], WqS[pi], aq2);
        ak2 = fmaf(w2*k[c]*k[c2], WkS[pi], ak2);
      }
    }
    sqk = wave_sum(sqk);  ss  = wave_sum(ss);
    aq  = wave_sum(aq);   ak  = wave_sum(ak);
    aq2 = wave_sum(aq2);  ak2 = wave_sum(ak2);
    if (tx == 0){
      atomicAdd(&accb[g],      sqk);       atomicAdd(&accb[24+g],    ss);
      atomicAdd(&accb[8+g],    0.1f*aq);   atomicAdd(&accb[24+8+g],  0.01f*aq2);
      atomicAdd(&accb[16+g],   0.1f*ak);   atomicAdd(&accb[24+16+g], 0.01f*ak2);
    }
  }
}

// ---------------------------------------------------------------------------
// attention pass 2 (R13): phase A with paired-j KT b128 loads + dual
// accumulation chains; rest as R12. grid (1024 b, 8 g), block (64,4)
// ---------------------------------------------------------------------------
__global__ __launch_bounds__(256) void k_att2(const float* __restrict__ qk32,
    const ushort* __restrict__ vbf, const float* __restrict__ bq,
    const float* __restrict__ rel, const float* __restrict__ simsc,
    ushort* __restrict__ svout, float* __restrict__ accbo)
{
  __shared__ __align__(16) char smem[32768];
  float* REQT = (float*)(smem);            // [128][12] (8 used)
  float* REKT = (float*)(smem + 6144);
  float* KT   = (float*)(smem + 12288);    // [64][8]
  float* MP   = (float*)(smem + 30720);    // [4][64]
  float* SP   = (float*)(smem + 31744);    // [4][64]
  float* RINV = (float*)(smem + 30720);    // aliases MP (dead after bar2)

  const int b = blockIdx.x, g = blockIdx.y;
  const int tx = threadIdx.x, ty = threadIdx.y;
  const int tid = ty*64 + tx;
  const float scq  = simsc[g];
  const float scr_ = 0.1f*simsc[8+g];
  const float sck_ = 0.1f*simsc[16+g];

  // ---- staging ----
  if (tid < 128){                          // KT[j][c] = bn(k[c][j])
    int j = tid & 63, h = tid >> 6;
    f32x4 kv;
    #pragma unroll
    for (int e = 0; e < 4; ++e){
      int o = g*32 + 8 + h*4 + e;
      kv[e] = fmaf(bq[o], qk32[((size_t)b*128 + g*16 + 8 + h*4 + e)*64 + j], bq[256+o]);
    }
    *(f32x4*)(KT + j*8 + h*4) = kv;
  }
  if (tid < 254){                          // REQT/REKT rows (scale folded)
    int side = tid >= 127;
    int d = tid - side*127;
    float rs = side ? sck_ : scr_;
    float* dst = (side ? REKT : REQT) + d*12;
    f32x4 r0, r1;
    #pragma unroll
    for (int e = 0; e < 4; ++e) r0[e] = rel[(side*8 + e)*127 + d]*rs;
    #pragma unroll
    for (int e = 0; e < 4; ++e) r1[e] = rel[(side*8 + 4 + e)*127 + d]*rs;
    *(f32x4*)dst = r0; *(f32x4*)(dst+4) = r1;
  }
  {
    // VB[c][j] bf16 (16 rows x 128B), chunk-XOR swizzle
    int c = tid >> 4, j4 = (tid & 15)*4;
    int o = g*32 + 16 + c;
    float gsc = bq[o], gsh = bq[256+o];
    const ushort* src = &vbf[((size_t)b*128 + g*16 + c)*64 + j4];
    bf16x4 pv;
    #pragma unroll
    for (int e = 0; e < 4; ++e) pv[e] = (short)f2bf(fmaf(gsc, bf2f(src[e]), gsh));
    *(bf16x4*)(smem + 24576 + c*128 + (((j4>>3) ^ (c&7))<<4) + (j4&7)*2) = pv;
  }
  {
    // REB[c][d] = 0.1*rel[16+c][d] bf16 (16 rows x 256B), swizzled
    int c = tid >> 4, d8 = (tid & 15)*8;
    const float* rsrc = &rel[(16+c)*127 + d8];
    bf16x8 pk;
    #pragma unroll
    for (int e = 0; e < 8; ++e){
      int d = d8 + e;
      pk[e] = (d < 127) ? (short)f2bf(0.1f*rsrc[e]) : (short)0;
    }
    *(bf16x8*)(smem + 26624 + c*256 + (((d8>>3) ^ (c&15))<<4)) = pk;
  }
  float q8[8], qs8[8];                     // per-lane q (i = tx), scq-folded copy
  #pragma unroll
  for (int c = 0; c < 8; ++c){
    int o = g*32 + c;
    float qv = fmaf(bq[o], qk32[((size_t)b*128 + g*16 + c)*64 + tx], bq[256+o]);
    q8[c] = qv; qs8[c] = scq*qv;
  }
  __syncthreads();                          // bar0

  // ---- phase A: lane = i = tx; wave ty covers j = ty*16..+15 (paired) ----
  float acc[16];
  {
    const int j0 = ty*16;
    const f32x2* q2  = (const f32x2*)q8;
    const f32x2* qs2 = (const f32x2*)qs8;
    #pragma unroll
    for (int p = 0; p < 8; ++p){
      const int j = j0 + 2*p;
      float kbuf[16];
      *(f32x4*)(kbuf+0)  = *(const f32x4*)(KT + j*8 + 0);
      *(f32x4*)(kbuf+4)  = *(const f32x4*)(KT + j*8 + 4);
      *(f32x4*)(kbuf+8)  = *(const f32x4*)(KT + j*8 + 8);
      *(f32x4*)(kbuf+12) = *(const f32x4*)(KT + j*8 + 12);
      const f32x2* ktA = (const f32x2*)(kbuf);
      const f32x2* ktB = (const f32x2*)(kbuf + 8);
      const f32x2* rqA = (const f32x2*)(REQT + (tx - j + 63)*12);
      const f32x2* rqB = (const f32x2*)(REQT + (tx - j + 62)*12);
      const f32x2* rkA = (const f32x2*)(REKT + (j - tx + 63)*12);
      const f32x2* rkB = (const f32x2*)(REKT + (j - tx + 64)*12);
      f32x2 aA = (f32x2){0.f,0.f}, bA = (f32x2){0.f,0.f};
      f32x2 aB = (f32x2){0.f,0.f}, bB = (f32x2){0.f,0.f};
      #pragma unroll
      for (int c2 = 0; c2 < 4; ++c2){
        f32x2 kvA = ktA[c2], kvB = ktB[c2];
        aA = __builtin_elementwise_fma(qs2[c2], kvA,     aA);
        aA = __builtin_elementwise_fma(q2[c2],  rqA[c2], aA);
        bA = __builtin_elementwise_fma(kvA,     rkA[c2], bA);
        aB = __builtin_elementwise_fma(qs2[c2], kvB,     aB);
        aB = __builtin_elementwise_fma(q2[c2],  rqB[c2], aB);
        bB = __builtin_elementwise_fma(kvB,     rkB[c2], bB);
      }
      acc[2*p]     = (aA.x + aA.y) + (bA.x + bA.y);
      acc[2*p + 1] = (aB.x + aB.y) + (bB.x + bB.y);
    }
  }
  // per-thread partial max
  {
    float m0 = fmaxf(fmaxf(acc[0],acc[1]),  fmaxf(acc[2],acc[3]));
    float m1 = fmaxf(fmaxf(acc[4],acc[5]),  fmaxf(acc[6],acc[7]));
    float m2 = fmaxf(fmaxf(acc[8],acc[9]),  fmaxf(acc[10],acc[11]));
    float m3 = fmaxf(fmaxf(acc[12],acc[13]),fmaxf(acc[14],acc[15]));
    MP[ty*64 + tx] = fmaxf(fmaxf(m0,m1), fmaxf(m2,m3));
  }
  __syncthreads();                          // bar1: REQT/REKT/KT dead

  // ---- zero PP + row max + exp + partial sums ----
  {
    f32x4 z = (f32x4){0.f,0.f,0.f,0.f};
    float* zp = (float*)(smem + 8192 + tid*64);
    *(f32x4*)(zp+0) = z; *(f32x4*)(zp+4) = z;
    *(f32x4*)(zp+8) = z; *(f32x4*)(zp+12) = z;
  }
  {
    float mrow = fmaxf(fmaxf(MP[tx], MP[64+tx]), fmaxf(MP[128+tx], MP[192+tx]));
    float s = 0.f;
    #pragma unroll
    for (int t = 0; t < 16; ++t){ float ex = __expf(acc[t]-mrow); acc[t] = ex; s += ex; }
    SP[ty*64 + tx] = s;
  }
  __syncthreads();                          // bar2: MP dead (RINV aliases)

  // ---- RINV + PB/PP writes from registers ----
  if (ty == 0)
    RINV[tx] = 1.0f / ((SP[tx] + SP[64+tx]) + (SP[128+tx] + SP[192+tx]));
  {
    bf16x8 pk0, pk1;
    #pragma unroll
    for (int e = 0; e < 8; ++e){ pk0[e] = (short)f2bf(acc[e]); pk1[e] = (short)f2bf(acc[8+e]); }
    char* pbbase = smem + 0 + tx*128;
    *(bf16x8*)(pbbase + (((2*ty    ) ^ (tx&7))<<4)) = pk0;
    *(bf16x8*)(pbbase + (((2*ty + 1) ^ (tx&7))<<4)) = pk1;
    char* ppbase = smem + 8192 + tx*256;
    #pragma unroll
    for (int e = 0; e < 16; ++e){
      int j = ty*16 + e, d = tx - j + 63;
      *(ushort*)(ppbase + (((d>>3) ^ (tx&15))<<4) + (d&7)*2) = f2bf(acc[e]);
    }
  }
  __syncthreads();                          // bar3

  // ---- phase C: MFMA. wave ty: output rows i0..i0+15, cols = 16 channels ----
  {
    const int l15 = tx & 15, lg = tx >> 4;
    const int i0 = ty*16;
    const int rowA = i0 + l15;
    char* pbA = smem + 0    + rowA*128;
    char* ppA = smem + 8192 + rowA*256;
    char* vbB = smem + 24576 + l15*128;
    char* reB = smem + 26624 + l15*256;
    f32x4 accv = (f32x4){0.f,0.f,0.f,0.f};
    f32x4 acce = (f32x4){0.f,0.f,0.f,0.f};
    #pragma unroll
    for (int kk = 0; kk < 2; ++kk){
      bf16x8 a  = *(bf16x8*)(pbA + (((kk*4+lg) ^ (rowA&7))<<4));
      bf16x8 bb = *(bf16x8*)(vbB + (((kk*4+lg) ^ (l15&7))<<4));
      accv = __builtin_amdgcn_mfma_f32_16x16x32_bf16(a, bb, accv, 0, 0, 0);
    }
    #pragma unroll
    for (int kk = 0; kk < 4; ++kk){
      bf16x8 a  = *(bf16x8*)(ppA + (((kk*4+lg) ^ (rowA&15))<<4));
      bf16x8 bb = *(bf16x8*)(reB + (((kk*4+lg) ^ (l15&15))<<4));
      acce = __builtin_amdgcn_mfma_f32_16x16x32_bf16(a, bb, acce, 0, 0, 0);
    }
    f32x4 ri4 = *(f32x4*)(smem + 30720 + (i0 + lg*4)*4);
    float* accb = accbo + (size_t)(b & (NCOPY-1)) * 512;
    {
      bf16x4 vb4;
      float vsum = 0.f, vsq = 0.f;
      #pragma unroll
      for (int r = 0; r < 4; ++r){
        float v = accv[r]*ri4[r];
        vb4[r] = (short)f2bf(v); vsum += v; vsq = fmaf(v, v, vsq);
      }
      int ch = g*16 + l15;
      *(bf16x4*)&svout[((size_t)b*256 + ch)*64 + i0 + lg*4] = vb4;
      vsum += __shfl_xor(vsum, 16, 64); vsum += __shfl_xor(vsum, 32, 64);
      vsq  += __shfl_xor(vsq , 16, 64); vsq  += __shfl_xor(vsq , 32, 64);
      if (lg == 0){ atomicAdd(&accb[ch], vsum); atomicAdd(&accb[256+ch], vsq); }
    }
    {
      bf16x4 vb4;
      float vsum = 0.f, vsq = 0.f;
      #pragma unroll
      for (int r = 0; r < 4; ++r){
        float v = acce[r]*ri4[r];
        vb4[r] = (short)f2bf(v); vsum += v; vsq = fmaf(v, v, vsq);
      }
      int ch = 128 + g*16 + l15;
      *(bf16x4*)&svout[((size_t)b*256 + ch)*64 + i0 + lg*4] = vb4;
      vsum += __shfl_xor(vsum, 16, 64); vsum += __shfl_xor(vsum, 32, 64);
      vsq  += __shfl_xor(vsq , 16, 64); vsq  += __shfl_xor(vsq , 32, 64);
      if (lg == 0){ atomicAdd(&accb[ch], vsum); atomicAdd(&accb[256+ch], vsq); }
    }
  }
}

// ---------------------------------------------------------------------------
// bo-BN + pair-sum + transpose (uint-vectorized)
// ---------------------------------------------------------------------------
__global__ __launch_bounds__(256) void k_pairT(const ushort* __restrict__ sv,
    const float* __restrict__ bo, ushort* __restrict__ win)
{
  __shared__ float t[64][66];
  const int c = blockIdx.x, n = blockIdx.y;
  const int tid = threadIdx.x;
  const float s0 = bo[2*c], s1 = bo[2*c+1];
  const float sh = bo[256 + 2*c] + bo[256 + 2*c + 1];
  const ushort* base = sv + (size_t)(n*64)*256*64;
  #pragma unroll
  for (int r = 0; r < 8; ++r){
    int u = tid + r*256;
    int w = u >> 5, hp = u & 31;
    uint a = *(const uint*)&base[((size_t)w*256 + 2*c    )*64 + 2*hp];
    uint bwd = *(const uint*)&base[((size_t)w*256 + 2*c + 1)*64 + 2*hp];
    float a0 = bf2f((ushort)a),   a1 = bf2f((ushort)(a >> 16));
    float b0 = bf2f((ushort)bwd), b1 = bf2f((ushort)(bwd >> 16));
    f32x2 vv;
    vv.x = fmaf(s0, a0, fmaf(s1, b0, sh));
    vv.y = fmaf(s0, a1, fmaf(s1, b1, sh));
    *(f32x2*)&t[w][2*hp] = vv;
  }
  __syncthreads();
  uint* dst = (uint*)(win + (size_t)(n*64)*8192 + (size_t)c*64);
  #pragma unroll
  for (int r = 0; r < 8; ++r){
    int u = tid + r*256;
    int h = u >> 5, wp = u & 31;
    float v0 = t[2*wp    ][h];
    float v1 = t[2*wp + 1][h];
    dst[(size_t)h*4096 + wp] = ((uint)f2bf(v1) << 16) | f2bf(v0);
  }
}

// ---------------------------------------------------------------------------
// bo-BN + pair-sum, no transpose (uint-vectorized)
// ---------------------------------------------------------------------------
__global__ __launch_bounds__(256) void k_pair_w(const ushort* __restrict__ sv,
    const float* __restrict__ bo, ushort* __restrict__ wbuf)
{
  const int m = blockIdx.x, n = blockIdx.y;
  const int tid = threadIdx.x;
  const float s0 = bo[2*m], s1 = bo[2*m+1];
  const float sh = bo[256 + 2*m] + bo[256 + 2*m + 1];
  const uint* p0 = (const uint*)(sv + ((size_t)(n*64)*256 + 2*m    )*64);
  const uint* p1 = (const uint*)(sv + ((size_t)(n*64)*256 + 2*m + 1)*64);
  uint* dst = (uint*)(wbuf + ((size_t)(n*128 + m)*64)*64);
  #pragma unroll
  for (int r = 0; r < 8; ++r){
    int u = tid + r*256;
    int h = u >> 5, wp = u & 31;
    uint a = p0[(size_t)h*8192 + wp];
    uint bwd = p1[(size_t)h*8192 + wp];
    float a0 = bf2f((ushort)a),   a1 = bf2f((ushort)(a >> 16));
    float b0 = bf2f((ushort)bwd), b1 = bf2f((ushort)(bwd >> 16));
    float r0 = fmaf(s0, a0, fmaf(s1, b0, sh));
    float r1 = fmaf(s0, a1, fmaf(s1, b1, sh));
    dst[(size_t)u] = ((uint)f2bf(r1) << 16) | f2bf(r0);
  }
}

// ---------------------------------------------------------------------------

extern "C" void kernel_launch(void* const* d_in, const int* in_sizes, int n_in,
                              void* d_out, int out_size, void* d_ws, size_t ws_size,
                              hipStream_t stream)
{
  const float* x     = (const float*)d_in[0];
  const float* c1_w  = (const float*)d_in[1];
  const float* c1_b  = (const float*)d_in[2];
  const float* cd_w  = (const float*)d_in[3];
  const float* cd_b  = (const float*)d_in[4];
  const float* bn1_g = (const float*)d_in[5];
  const float* bn1_b = (const float*)d_in[6];
  const float* h_qkv = (const float*)d_in[7];
  const float* h_bqg = (const float*)d_in[8];
  const float* h_bqb = (const float*)d_in[9];
  const float* h_bsg = (const float*)d_in[10];
  const float* h_bsb = (const float*)d_in[11];
  const float* h_bog = (const float*)d_in[12];
  const float* h_bob = (const float*)d_in[13];
  const float* h_rel = (const float*)d_in[14];
  const float* w_qkv = (const float*)d_in[15];
  const float* w_bqg = (const float*)d_in[16];
  const float* w_bqb = (const float*)d_in[17];
  const float* w_bsg = (const float*)d_in[18];
  const float* w_bsb = (const float*)d_in[19];
  const float* w_bog = (const float*)d_in[20];
  const float* w_bob = (const float*)d_in[21];
  const float* w_rel = (const float*)d_in[22];
  const float* cu_w  = (const float*)d_in[23];
  const float* cu_b  = (const float*)d_in[24];
  const float* bn2_g = (const float*)d_in[25];
  const float* bn2_b = (const float*)d_in[26];
  float* out = (float*)d_out;
  char* ws = (char*)d_ws;

  // big buffers (aliased across dead stages):
  ushort* OUT0  = (ushort*)(ws + 0);                  // 16MB bf16 (n,128,4096)
  ushort* HIN   = (ushort*)(ws + (32ull<<20));        // 16MB bf16 (1024,128,64)
  float*  QK32H = (float*)(ws + (64ull<<20));         // 32MB fp32 (1024,128,64)
  ushort* VBFH  = (ushort*)(ws + (96ull<<20));        // 16MB bf16 (1024,128,64)
  ushort* SVO   = (ushort*)(ws + 0);                  // 32MB bf16, after OUT0/HIN dead
  ushort* WIN   = (ushort*)(ws + (64ull<<20));        // 16MB bf16, after QK32H dead
  float*  QK32W = (float*)(ws + (96ull<<20));         // 32MB fp32, after VBFH dead
  ushort* VBFW  = (ushort*)(ws + (128ull<<20));       // 16MB bf16
  ushort* WBUF  = (ushort*)(ws + (64ull<<20));        // 16MB bf16, after WIN dead
  ushort* Y2    = (ushort*)(ws + (96ull<<20));        // 32MB bf16, after QK32W dead
  float*  ST    = (float*)(ws + (160ull<<20));        // stats region

  // NCOPY=64 spread accumulators (sizes in floats):
  float* ACC_BN1 = ST;             // 16384
  float* ACC_BQ  = ST + 16384;     // 32768
  float* ACC_SIM = ST + 49152;     // 3072
  float* ACC_BO  = ST + 52224;     // 32768
  float* ACC_BQW = ST + 84992;     // 32768
  float* ACC_SIMW= ST + 117760;    // 3072
  float* ACC_BOW = ST + 120832;    // 32768
  float* ACC_BN2 = ST + 153600;    // 32768  -> ACC total 186368 floats
  float* SCB     = ST + 186368;
  float* SC_BN1 = SCB;        float* SC_BQ  = SCB + 256;
  float* SC_SIM = SCB + 768;  float* SC_BO  = SCB + 816;
  float* SC_BQW = SCB + 1328; float* SC_SIMW= SCB + 1840;
  float* SC_BOW = SCB + 1888; float* SC_BN2 = SCB + 2400;  // -> 2912
  float* RWH  = ST + 189280;  // packed: 5632 floats used (9216 reserved)
  float* RWW  = ST + 198496;  // packed: 5632 floats used
  // bf16 weights (contiguous):
  ushort* CDBF = (ushort*)(ST + 207712);   // 16384
  ushort* QHBF = CDBF + 16384;             // 32768
  ushort* QWBF = CDBF + 49152;             // 32768
  ushort* CUBF = CDBF + 81920;             // 32768
  ushort* C1BF = CDBF + 114688;            // 32768 (end 147456 ushorts)

  hipMemsetAsync(ST, 0, 186368*sizeof(float), stream);

  const dim3 blk(64,4);
  const float inv64k = 1.f/65536.f;
  const float invsim = 1.f/4194304.f;

  // merged weight conversion + packed rel prep
  k_pre<<<580, 256, 0, stream>>>(cd_w, h_qkv, w_qkv, cu_w, c1_w, CDBF,
                                 h_rel, w_rel, RWH, RWW);

  // cd conv + bn1 stats
  k_gemm<128,0,12,0,1><<<1024, 256, 0, stream>>>(x, CDBF, cd_b, OUT0, ACC_BN1, nullptr, nullptr, nullptr);
  k_finalize<<<1, 128, 0, stream>>>(ACC_BN1, bn1_g, bn1_b, SC_BN1, 128, inv64k);
  k_trans_bnrelu<<<dim3(128,16), 256, 0, stream>>>(OUT0, SC_BN1, HIN);

  // ---- h axial ----
  k_gemm<256,3,6,1,0><<<1024, 256, 0, stream>>>(HIN, QHBF, nullptr, QK32H, ACC_BQ, nullptr, nullptr, VBFH);
  k_finalize<<<1, 256, 0, stream>>>(ACC_BQ, h_bqg, h_bqb, SC_BQ, 256, inv64k);
  k_att_stats<<<1024, blk, 0, stream>>>(QK32H, SC_BQ, RWH, ACC_SIM);
  k_finalize<<<1, 32, 0, stream>>>(ACC_SIM, h_bsg, h_bsb, SC_SIM, 24, invsim);
  k_att2<<<dim3(1024,8), blk, 0, stream>>>(QK32H, VBFH, SC_BQ, h_rel, SC_SIM, SVO, ACC_BO);
  k_finalize<<<1, 256, 0, stream>>>(ACC_BO, h_bog, h_bob, SC_BO, 256, inv64k);
  k_pairT<<<dim3(128,16), 256, 0, stream>>>(SVO, SC_BO, WIN);

  // ---- w axial ----
  k_gemm<256,3,6,1,0><<<1024, 256, 0, stream>>>(WIN, QWBF, nullptr, QK32W, ACC_BQW, nullptr, nullptr, VBFW);
  k_finalize<<<1, 256, 0, stream>>>(ACC_BQW, w_bqg, w_bqb, SC_BQW, 256, inv64k);
  k_att_stats<<<1024, blk, 0, stream>>>(QK32W, SC_BQW, RWW, ACC_SIMW);
  k_finalize<<<1, 32, 0, stream>>>(ACC_SIMW, w_bsg, w_bsb, SC_SIMW, 24, invsim);
  k_att2<<<dim3(1024,8), blk, 0, stream>>>(QK32W, VBFW, SC_BQW, w_rel, SC_SIMW, SVO, ACC_BOW);
  k_finalize<<<1, 256, 0, stream>>>(ACC_BOW, w_bog, w_bob, SC_BOW, 256, inv64k);
  k_pair_w<<<dim3(128,16), 256, 0, stream>>>(SVO, SC_BOW, WBUF);

  // cu conv + bn2 stats, then fused residual + c1 conv
  k_gemm<256,0,12,1,1><<<1024, 256, 0, stream>>>(WBUF, CUBF, cu_b, Y2, ACC_BN2, nullptr, nullptr, nullptr);
  k_finalize<<<1, 256, 0, stream>>>(ACC_BN2, bn2_g, bn2_b, SC_BN2, 256, inv64k);
  k_gemm<256,2,12,0,0><<<1024, 256, 0, stream>>>(x, C1BF, c1_b, out, nullptr, Y2, SC_BN2, nullptr);
}

// Round 14
// 372.626 us; speedup vs baseline: 1.0095x; 1.0095x over previous
//
#include <hip/hip_runtime.h>

// ---------------------------------------------------------------------------
// AxialBlock fused implementation. Round 14: k_att2 phase-A rel reads as
// b128 (half the LDS issue stream) + f2bf-once reuse for PB/PP (bit-exact).
// NB=16, CIN=128, COUT=256, MID=128, G=8, GP=16, K=64
// ---------------------------------------------------------------------------

#define NCOPY 64

typedef __attribute__((ext_vector_type(8))) short bf16x8;
typedef __attribute__((ext_vector_type(4))) short bf16x4;
typedef __attribute__((ext_vector_type(4))) float f32x4;
typedef __attribute__((ext_vector_type(2))) float f32x2;

__device__ __forceinline__ float wave_sum(float v){
  #pragma unroll
  for (int o = 32; o; o >>= 1) v += __shfl_xor(v, o, 64);
  return v;
}
__device__ __forceinline__ ushort f2bf(float f){
  union { float f; unsigned u; } v; v.f = f;
  unsigned r = v.u + 0x7FFFu + ((v.u >> 16) & 1u);   // round-to-nearest-even
  return (ushort)(r >> 16);
}
__device__ __forceinline__ float bf2f(ushort u){
  union { unsigned u; float f; } v; v.u = ((unsigned)u) << 16;
  return v.f;
}

// ---------------------------------------------------------------------------
// merged pre-pass: blocks 0..575 = weight fp32->bf16; 576..579 = rel
// windowed sums/correlations (PACKED upper-triangle: 36 pairs).
// ---------------------------------------------------------------------------
__global__ void k_pre(const float* __restrict__ s0, const float* __restrict__ s1,
                      const float* __restrict__ s2, const float* __restrict__ s3,
                      const float* __restrict__ s4, ushort* __restrict__ dst,
                      const float* __restrict__ relh, const float* __restrict__ relw,
                      float* __restrict__ rwh, float* __restrict__ rww){
  const int blk = blockIdx.x;
  if (blk < 576){
    int i = blk*256 + threadIdx.x;
    if (i >= 147456) return;
    float v;
    if      (i < 16384)  v = s0[i];
    else if (i < 49152)  v = s1[i-16384];
    else if (i < 81920)  v = s2[i-49152];
    else if (i < 114688) v = s3[i-81920];
    else                 v = s4[i-114688];
    dst[i] = f2bf(v);
  } else {
    const int sidx = blk - 576;
    const float* rel = (sidx & 2) ? relw : relh;
    float* rw        = (sidx & 2) ? rww  : rwh;
    const int side = sidx & 1;
    const float* base = rel + side*8*127;
    float* Wout = rw + side*2304;
    float* Sout = rw + 4608 + side*512;
    const int tid = threadIdx.x;
    for (int idx = tid; idx < 2304; idx += 256){
      int pr = idx >> 6, i = idx & 63;
      int c = 0, off = pr;
      #pragma unroll
      for (int cc = 0; cc < 7; ++cc){ if (off >= 8 - c){ off -= (8 - c); ++c; } }
      int c2 = c + off;
      const float* r1 = base + c*127 + i;
      const float* r2 = base + c2*127 + i;
      float s = 0.f;
      #pragma unroll 8
      for (int u = 0; u < 64; ++u) s = fmaf(r1[u], r2[u], s);
      Wout[idx] = s;
    }
    for (int idx = tid; idx < 512; idx += 256){
      int c = idx >> 6, i = idx & 63;
      const float* r1 = base + c*127 + i;
      float s = 0.f;
      #pragma unroll 8
      for (int u = 0; u < 64; ++u) s += r1[u];
      Sout[idx] = s;
    }
  }
}

// ---------------------------------------------------------------------------
// MFMA GEMM: out[o][col] = sum_c Wb[o][c] * X[c][col]  (+ epilogue per MODE)
// MODE 0: + bias, write, stats.  MODE 1: write, stats.  MODE 2: + bias +
// scsh*y2(bf16) residual, write, no stats.  MODE 3: qkv split write
// (even 16-row subtiles = q/k fp32 -> out_; odd = v bf16 -> vout) + stats.
// ---------------------------------------------------------------------------
template<int O, int MODE, int SLOG, int INBF, int OUTBF>
__global__ __launch_bounds__(256) void k_gemm(
    const void* __restrict__ X_, const ushort* __restrict__ Wb,
    const float* __restrict__ bias, void* __restrict__ out_,
    float* __restrict__ acc, const ushort* __restrict__ y2,
    const float* __restrict__ scsh, ushort* __restrict__ vout)
{
  constexpr int RPW = O/4;       // rows per wave
  constexpr int NS  = RPW/16;    // 16-row subtiles per wave
  __shared__ ushort XT[64*128];  // [col][k] bf16, chunk-XOR swizzled

  const int tid = threadIdx.x;
  const int col0 = blockIdx.x << 6;
  const int seg  = col0 >> SLOG;
  const int p0   = col0 & ((1<<SLOG)-1);

  // ---- stage X tile (128c x 64col) -> bf16 transposed+swizzled ----
  {
    const int col = tid & 63;
    const int kc8 = tid >> 6;                  // 0..3
    #pragma unroll
    for (int q = 0; q < 4; ++q){
      int kc = kc8*4 + q;                      // k-chunk 0..15 (8 c's each)
      int c0 = kc*8;
      bf16x8 pk;
      if constexpr (INBF){
        const ushort* xb = (const ushort*)X_ + (((size_t)seg*128) << SLOG) + p0 + col;
        #pragma unroll
        for (int j = 0; j < 8; ++j)
          pk[j] = (short)xb[(size_t)(c0+j) << SLOG];
      } else {
        const float* xb = (const float*)X_ + (((size_t)seg*128) << SLOG) + p0 + col;
        #pragma unroll
        for (int j = 0; j < 8; ++j)
          pk[j] = (short)f2bf(xb[(size_t)(c0+j) << SLOG]);
      }
      *(bf16x8*)&XT[col*128 + ((kc ^ (col & 15)) << 3)] = pk;
    }
  }
  __syncthreads();

  const int lane = tid & 63;
  const int wid  = tid >> 6;
  const int l15  = lane & 15, lg = lane >> 4;

  f32x4 accr[NS][4];
  #pragma unroll
  for (int s = 0; s < NS; ++s)
    #pragma unroll
    for (int ns = 0; ns < 4; ++ns)
      accr[s][ns] = (f32x4){0.f,0.f,0.f,0.f};

  #pragma unroll
  for (int kk = 0; kk < 4; ++kk){
    bf16x8 af[NS];
    #pragma unroll
    for (int s = 0; s < NS; ++s){
      int m = wid*RPW + s*16 + l15;
      af[s] = *(const bf16x8*)(Wb + (size_t)m*128 + kk*32 + lg*8);
    }
    bf16x8 bfr[4];
    #pragma unroll
    for (int ns = 0; ns < 4; ++ns){
      int ncol  = ns*16 + l15;
      int chunk = kk*4 + lg;
      bfr[ns] = *(const bf16x8*)&XT[ncol*128 + ((chunk ^ l15) << 3)];
    }
    #pragma unroll
    for (int s = 0; s < NS; ++s)
      #pragma unroll
      for (int ns = 0; ns < 4; ++ns)
        accr[s][ns] = __builtin_amdgcn_mfma_f32_16x16x32_bf16(
                        af[s], bfr[ns], accr[s][ns], 0, 0, 0);
  }

  // ---- epilogue ----
  float* accb = (MODE != 2) ? acc + (size_t)(blockIdx.x & (NCOPY-1))*2*O : nullptr;
  #pragma unroll
  for (int s = 0; s < NS; ++s){
    #pragma unroll
    for (int r = 0; r < 4; ++r){
      const int m = wid*RPW + s*16 + lg*4 + r;
      const float bs = (MODE == 0 || MODE == 2) ? bias[m] : 0.f;
      float vsum = 0.f, vsq = 0.f;
      #pragma unroll
      for (int ns = 0; ns < 4; ++ns){
        float v = accr[s][ns][r] + bs;
        if constexpr (MODE == 3){
          const int cm = ((m >> 5) << 4) + (m & 15);
          size_t oidx = (((size_t)seg*128 + cm) << SLOG) + p0 + ns*16 + l15;
          if ((s & 1) == 0) ((float*)out_)[oidx] = v;    // q,k fp32
          else              vout[oidx] = f2bf(v);        // v bf16
        } else {
          size_t oidx = (((size_t)seg*O + m) << SLOG) + p0 + ns*16 + l15;
          if (MODE == 2)
            v += fmaf(scsh[m], bf2f(y2[oidx]), scsh[O+m]);
          if constexpr (OUTBF) ((ushort*)out_)[oidx] = f2bf(v);
          else                 ((float*) out_)[oidx] = v;
        }
        vsum += v; vsq = fmaf(v, v, vsq);
      }
      if (MODE != 2){
        #pragma unroll
        for (int o2 = 1; o2 < 16; o2 <<= 1){
          vsum += __shfl_xor(vsum, o2, 64);
          vsq  += __shfl_xor(vsq , o2, 64);
        }
        if (l15 == 0){
          atomicAdd(&accb[m],   vsum);
          atomicAdd(&accb[O+m], vsq);
        }
      }
    }
  }
}

// ---------------------------------------------------------------------------
// BN finalize: sum NCOPY copies; scsh[c]=g*rstd ; scsh[C+c]=b-mean*scale
// ---------------------------------------------------------------------------
__global__ void k_finalize(const float* __restrict__ acc, const float* __restrict__ g,
    const float* __restrict__ b, float* __restrict__ scsh, int C, float invcnt)
{
  int c = blockIdx.x*blockDim.x + threadIdx.x;
  if (c >= C) return;
  float s = 0.f, s2 = 0.f;
  #pragma unroll 4
  for (int k2 = 0; k2 < NCOPY; ++k2){
    s  += acc[(size_t)k2*2*C + c];
    s2 += acc[(size_t)k2*2*C + C + c];
  }
  float mean = s*invcnt;
  float var  = s2*invcnt - mean*mean;
  float sc = g[c]*rsqrtf(var + 1e-5f);
  scsh[c]   = sc;
  scsh[C+c] = fmaf(-mean, sc, b[c]);
}

// ---------------------------------------------------------------------------
// bn1+relu + transpose (uint-vectorized)
// ---------------------------------------------------------------------------
__global__ __launch_bounds__(256) void k_trans_bnrelu(const ushort* __restrict__ out0,
    const float* __restrict__ scsh, ushort* __restrict__ hin)
{
  __shared__ float t[64][66];
  const int c = blockIdx.x, n = blockIdx.y;
  const int tid = threadIdx.x;
  const float sc = scsh[c], sh = scsh[128+c];
  const uint* src = (const uint*)(out0 + ((size_t)n*128 + c)*4096);
  #pragma unroll
  for (int r = 0; r < 8; ++r){
    int u = tid + r*256;
    uint a = src[u];
    f32x2 vv; vv.x = bf2f((ushort)a); vv.y = bf2f((ushort)(a >> 16));
    *(f32x2*)&t[u >> 5][(u & 31)*2] = vv;
  }
  __syncthreads();
  uint* dst = (uint*)(hin + (size_t)(n*64)*8192 + (size_t)c*64);
  #pragma unroll
  for (int r = 0; r < 8; ++r){
    int u = tid + r*256;
    int w = u >> 5, hp = u & 31;
    float v0 = fmaxf(fmaf(sc, t[2*hp    ][w], sh), 0.f);
    float v1 = fmaxf(fmaf(sc, t[2*hp + 1][w], sh), 0.f);
    dst[(size_t)w*4096 + hp] = ((uint)f2bf(v1) << 16) | f2bf(v0);
  }
}

// ---------------------------------------------------------------------------
// sim-BN stats per (b,g): Gram + rowsums via MFMA; PACKED upper-tri tables
// (22.5KB LDS -> 7 blocks/CU). grid (1024), block (64,4)
// ---------------------------------------------------------------------------
__global__ __launch_bounds__(256, 7) void k_att_stats(const float* __restrict__ qk32,
    const float* __restrict__ bq, const float* __restrict__ rw, float* __restrict__ accsim)
{
  __shared__ float WqS[2304], WkS[2304], SqS[512], SkS[512];
  const int b = blockIdx.x;
  const int tx = threadIdx.x, ty = threadIdx.y;
  const int tid = ty*64 + tx;
  for (int idx = tid; idx < 2304; idx += 256){ WqS[idx] = rw[idx]; WkS[idx] = rw[2304+idx]; }
  for (int idx = tid; idx < 512;  idx += 256){ SqS[idx] = rw[4608+idx]; SkS[idx] = rw[5120+idx]; }
  __syncthreads();
  float* accb = accsim + (size_t)(b & (NCOPY-1)) * 48;
  const int i = tx;
  const int l15 = tx & 15, lg = tx >> 4;
  const short one_bf = (short)0x3F80;
  const bf16x8 ones = {one_bf,one_bf,one_bf,one_bf,one_bf,one_bf,one_bf,one_bf};
  constexpr int tb[8] = {0,8,15,21,26,30,33,35};

  #pragma unroll
  for (int gi = 0; gi < 2; ++gi){
    const int g = ty*2 + gi;
    float q[8], k[8];
    #pragma unroll
    for (int c = 0; c < 8; ++c){
      int oq = g*32 + c, ok = oq + 8;
      q[c] = fmaf(bq[oq], qk32[((size_t)b*128 + g*16 + c    )*64 + i], bq[256+oq]);
      k[c] = fmaf(bq[ok], qk32[((size_t)b*128 + g*16 + 8 + c)*64 + i], bq[256+ok]);
    }
    const int och = g*32 + l15;
    const float gsc = bq[och], gsh = bq[256+och];
    const float* src = &qk32[((size_t)b*128 + g*16 + l15)*64 + lg*8];
    bf16x8 a0, a1;
    #pragma unroll
    for (int j = 0; j < 8; ++j) a0[j] = (short)f2bf(fmaf(gsc, src[j],      gsh));
    #pragma unroll
    for (int j = 0; j < 8; ++j) a1[j] = (short)f2bf(fmaf(gsc, src[32 + j], gsh));
    f32x4 G = (f32x4){0.f,0.f,0.f,0.f};
    f32x4 R = (f32x4){0.f,0.f,0.f,0.f};
    G = __builtin_amdgcn_mfma_f32_16x16x32_bf16(a0, a0, G, 0, 0, 0);
    G = __builtin_amdgcn_mfma_f32_16x16x32_bf16(a1, a1, G, 0, 0, 0);
    R = __builtin_amdgcn_mfma_f32_16x16x32_bf16(a0, ones, R, 0, 0, 0);
    R = __builtin_amdgcn_mfma_f32_16x16x32_bf16(a1, ones, R, 0, 0, 0);
    float ss = 0.f, sqk = 0.f;
    const bool gq_lane = (l15 < 8) && (lg < 2);
    const bool r_lane  = (l15 == 0) && (lg < 2);
    #pragma unroll
    for (int r = 0; r < 4; ++r){
      float gsw = __shfl_xor(G[r], 40, 64);
      float rsw = __shfl_xor(R[r], 32, 64);
      if (gq_lane) ss  = fmaf(G[r], gsw, ss);
      if (r_lane)  sqk = fmaf(R[r], rsw, sqk);
    }
    float aq = 0.f, ak = 0.f, aq2 = 0.f, ak2 = 0.f;
    #pragma unroll
    for (int c = 0; c < 8; ++c){
      aq = fmaf(q[c], SqS[c*64 + i], aq);
      ak = fmaf(k[c], SkS[c*64 + i], ak);
    }
    #pragma unroll
    for (int c = 0; c < 8; ++c){
      #pragma unroll
      for (int c2 = c; c2 < 8; ++c2){
        float w2 = (c2 == c) ? 1.f : 2.f;
        int pi = (tb[c] + c2 - c)*64 + i;
        aq2 = fmaf(w2*q[c]*q[c2], WqS[pi], aq2);
        ak2 = fmaf(w2*k[c]*k[c2], WkS[pi], ak2);
      }
    }
    sqk = wave_sum(sqk);  ss  = wave_sum(ss);
    aq  = wave_sum(aq);   ak  = wave_sum(ak);
    aq2 = wave_sum(aq2);  ak2 = wave_sum(ak2);
    if (tx == 0){
      atomicAdd(&accb[g],      sqk);       atomicAdd(&accb[24+g],    ss);
      atomicAdd(&accb[8+g],    0.1f*aq);   atomicAdd(&accb[24+8+g],  0.01f*aq2);
      atomicAdd(&accb[16+g],   0.1f*ak);   atomicAdd(&accb[24+16+g], 0.01f*ak2);
    }
  }
}

// ---------------------------------------------------------------------------
// attention pass 2 (R14): phase-A rel reads as b128 (rbuf), f2bf-once for
// PB/PP. grid (1024 b, 8 g), block (64,4)
// ---------------------------------------------------------------------------
__global__ __launch_bounds__(256) void k_att2(const float* __restrict__ qk32,
    const ushort* __restrict__ vbf, const float* __restrict__ bq,
    const float* __restrict__ rel, const float* __restrict__ simsc,
    ushort* __restrict__ svout, float* __restrict__ accbo)
{
  __shared__ __align__(16) char smem[32768];
  float* REQT = (float*)(smem);            // [128][12] (8 used)
  float* REKT = (float*)(smem + 6144);
  float* KT   = (float*)(smem + 12288);    // [64][8]
  float* MP   = (float*)(smem + 30720);    // [4][64]
  float* SP   = (float*)(smem + 31744);    // [4][64]
  float* RINV = (float*)(smem + 30720);    // aliases MP (dead after bar2)

  const int b = blockIdx.x, g = blockIdx.y;
  const int tx = threadIdx.x, ty = threadIdx.y;
  const int tid = ty*64 + tx;
  const float scq  = simsc[g];
  const float scr_ = 0.1f*simsc[8+g];
  const float sck_ = 0.1f*simsc[16+g];

  // ---- staging ----
  if (tid < 128){                          // KT[j][c] = bn(k[c][j])
    int j = tid & 63, h = tid >> 6;
    f32x4 kv;
    #pragma unroll
    for (int e = 0; e < 4; ++e){
      int o = g*32 + 8 + h*4 + e;
      kv[e] = fmaf(bq[o], qk32[((size_t)b*128 + g*16 + 8 + h*4 + e)*64 + j], bq[256+o]);
    }
    *(f32x4*)(KT + j*8 + h*4) = kv;
  }
  if (tid < 254){                          // REQT/REKT rows (scale folded)
    int side = tid >= 127;
    int d = tid - side*127;
    float rs = side ? sck_ : scr_;
    float* dst = (side ? REKT : REQT) + d*12;
    f32x4 r0, r1;
    #pragma unroll
    for (int e = 0; e < 4; ++e) r0[e] = rel[(side*8 + e)*127 + d]*rs;
    #pragma unroll
    for (int e = 0; e < 4; ++e) r1[e] = rel[(side*8 + 4 + e)*127 + d]*rs;
    *(f32x4*)dst = r0; *(f32x4*)(dst+4) = r1;
  }
  {
    // VB[c][j] bf16 (16 rows x 128B), chunk-XOR swizzle
    int c = tid >> 4, j4 = (tid & 15)*4;
    int o = g*32 + 16 + c;
    float gsc = bq[o], gsh = bq[256+o];
    const ushort* src = &vbf[((size_t)b*128 + g*16 + c)*64 + j4];
    bf16x4 pv;
    #pragma unroll
    for (int e = 0; e < 4; ++e) pv[e] = (short)f2bf(fmaf(gsc, bf2f(src[e]), gsh));
    *(bf16x4*)(smem + 24576 + c*128 + (((j4>>3) ^ (c&7))<<4) + (j4&7)*2) = pv;
  }
  {
    // REB[c][d] = 0.1*rel[16+c][d] bf16 (16 rows x 256B), swizzled
    int c = tid >> 4, d8 = (tid & 15)*8;
    const float* rsrc = &rel[(16+c)*127 + d8];
    bf16x8 pk;
    #pragma unroll
    for (int e = 0; e < 8; ++e){
      int d = d8 + e;
      pk[e] = (d < 127) ? (short)f2bf(0.1f*rsrc[e]) : (short)0;
    }
    *(bf16x8*)(smem + 26624 + c*256 + (((d8>>3) ^ (c&15))<<4)) = pk;
  }
  float q8[8], qs8[8];                     // per-lane q (i = tx), scq-folded copy
  #pragma unroll
  for (int c = 0; c < 8; ++c){
    int o = g*32 + c;
    float qv = fmaf(bq[o], qk32[((size_t)b*128 + g*16 + c)*64 + tx], bq[256+o]);
    q8[c] = qv; qs8[c] = scq*qv;
  }
  __syncthreads();                          // bar0

  // ---- phase A: lane = i = tx; wave ty covers j = ty*16..+15 (paired);
  //      all LDS reads as b128 into register buffers ----
  float acc[16];
  {
    const int j0 = ty*16;
    const f32x2* q2  = (const f32x2*)q8;
    const f32x2* qs2 = (const f32x2*)qs8;
    #pragma unroll
    for (int p = 0; p < 8; ++p){
      const int j = j0 + 2*p;
      float kbuf[16];
      *(f32x4*)(kbuf+0)  = *(const f32x4*)(KT + j*8 + 0);
      *(f32x4*)(kbuf+4)  = *(const f32x4*)(KT + j*8 + 4);
      *(f32x4*)(kbuf+8)  = *(const f32x4*)(KT + j*8 + 8);
      *(f32x4*)(kbuf+12) = *(const f32x4*)(KT + j*8 + 12);
      float rbufA[16], rbufB[16];           // [0:8)=rq, [8:16)=rk
      {
        const float* rqa = REQT + (tx - j + 63)*12;
        const float* rka = REKT + (j - tx + 63)*12;
        *(f32x4*)(rbufA+0)  = *(const f32x4*)(rqa);
        *(f32x4*)(rbufA+4)  = *(const f32x4*)(rqa+4);
        *(f32x4*)(rbufA+8)  = *(const f32x4*)(rka);
        *(f32x4*)(rbufA+12) = *(const f32x4*)(rka+4);
        const float* rqb = REQT + (tx - j + 62)*12;
        const float* rkb = REKT + (j - tx + 64)*12;
        *(f32x4*)(rbufB+0)  = *(const f32x4*)(rqb);
        *(f32x4*)(rbufB+4)  = *(const f32x4*)(rqb+4);
        *(f32x4*)(rbufB+8)  = *(const f32x4*)(rkb);
        *(f32x4*)(rbufB+12) = *(const f32x4*)(rkb+4);
      }
      const f32x2* ktA = (const f32x2*)(kbuf);
      const f32x2* ktB = (const f32x2*)(kbuf + 8);
      const f32x2* rqA = (const f32x2*)(rbufA);
      const f32x2* rkA = (const f32x2*)(rbufA + 8);
      const f32x2* rqB = (const f32x2*)(rbufB);
      const f32x2* rkB = (const f32x2*)(rbufB + 8);
      f32x2 aA = (f32x2){0.f,0.f}, bA = (f32x2){0.f,0.f};
      f32x2 aB = (f32x2){0.f,0.f}, bB = (f32x2){0.f,0.f};
      #pragma unroll
      for (int c2 = 0; c2 < 4; ++c2){
        f32x2 kvA = ktA[c2], kvB = ktB[c2];
        aA = __builtin_elementwise_fma(qs2[c2], kvA,     aA);
        aA = __builtin_elementwise_fma(q2[c2],  rqA[c2], aA);
        bA = __builtin_elementwise_fma(kvA,     rkA[c2], bA);
        aB = __builtin_elementwise_fma(qs2[c2], kvB,     aB);
        aB = __builtin_elementwise_fma(q2[c2],  rqB[c2], aB);
        bB = __builtin_elementwise_fma(kvB,     rkB[c2], bB);
      }
      acc[2*p]     = (aA.x + aA.y) + (bA.x + bA.y);
      acc[2*p + 1] = (aB.x + aB.y) + (bB.x + bB.y);
    }
  }
  // per-thread partial max
  {
    float m0 = fmaxf(fmaxf(acc[0],acc[1]),  fmaxf(acc[2],acc[3]));
    float m1 = fmaxf(fmaxf(acc[4],acc[5]),  fmaxf(acc[6],acc[7]));
    float m2 = fmaxf(fmaxf(acc[8],acc[9]),  fmaxf(acc[10],acc[11]));
    float m3 = fmaxf(fmaxf(acc[12],acc[13]),fmaxf(acc[14],acc[15]));
    MP[ty*64 + tx] = fmaxf(fmaxf(m0,m1), fmaxf(m2,m3));
  }
  __syncthreads();                          // bar1: REQT/REKT/KT dead

  // ---- zero PP + row max + exp + partial sums ----
  {
    f32x4 z = (f32x4){0.f,0.f,0.f,0.f};
    float* zp = (float*)(smem + 8192 + tid*64);
    *(f32x4*)(zp+0) = z; *(f32x4*)(zp+4) = z;
    *(f32x4*)(zp+8) = z; *(f32x4*)(zp+12) = z;
  }
  {
    float mrow = fmaxf(fmaxf(MP[tx], MP[64+tx]), fmaxf(MP[128+tx], MP[192+tx]));
    float s = 0.f;
    #pragma unroll
    for (int t = 0; t < 16; ++t){ float ex = __expf(acc[t]-mrow); acc[t] = ex; s += ex; }
    SP[ty*64 + tx] = s;
  }
  __syncthreads();                          // bar2: MP dead (RINV aliases)

  // ---- RINV + PB/PP writes (f2bf computed ONCE, reused) ----
  if (ty == 0)
    RINV[tx] = 1.0f / ((SP[tx] + SP[64+tx]) + (SP[128+tx] + SP[192+tx]));
  {
    ushort pb[16];
    #pragma unroll
    for (int e = 0; e < 16; ++e) pb[e] = f2bf(acc[e]);
    bf16x8 pk0, pk1;
    #pragma unroll
    for (int e = 0; e < 8; ++e){ pk0[e] = (short)pb[e]; pk1[e] = (short)pb[8+e]; }
    char* pbbase = smem + 0 + tx*128;
    *(bf16x8*)(pbbase + (((2*ty    ) ^ (tx&7))<<4)) = pk0;
    *(bf16x8*)(pbbase + (((2*ty + 1) ^ (tx&7))<<4)) = pk1;
    char* ppbase = smem + 8192 + tx*256;
    #pragma unroll
    for (int e = 0; e < 16; ++e){
      int j = ty*16 + e, d = tx - j + 63;
      *(ushort*)(ppbase + (((d>>3) ^ (tx&15))<<4) + (d&7)*2) = pb[e];
    }
  }
  __syncthreads();                          // bar3

  // ---- phase C: MFMA. wave ty: output rows i0..i0+15, cols = 16 channels ----
  {
    const int l15 = tx & 15, lg = tx >> 4;
    const int i0 = ty*16;
    const int rowA = i0 + l15;
    char* pbA = smem + 0    + rowA*128;
    char* ppA = smem + 8192 + rowA*256;
    char* vbB = smem + 24576 + l15*128;
    char* reB = smem + 26624 + l15*256;
    f32x4 accv = (f32x4){0.f,0.f,0.f,0.f};
    f32x4 acce = (f32x4){0.f,0.f,0.f,0.f};
    #pragma unroll
    for (int kk = 0; kk < 2; ++kk){
      bf16x8 a  = *(bf16x8*)(pbA + (((kk*4+lg) ^ (rowA&7))<<4));
      bf16x8 bb = *(bf16x8*)(vbB + (((kk*4+lg) ^ (l15&7))<<4));
      accv = __builtin_amdgcn_mfma_f32_16x16x32_bf16(a, bb, accv, 0, 0, 0);
    }
    #pragma unroll
    for (int kk = 0; kk < 4; ++kk){
      bf16x8 a  = *(bf16x8*)(ppA + (((kk*4+lg) ^ (rowA&15))<<4));
      bf16x8 bb = *(bf16x8*)(reB + (((kk*4+lg) ^ (l15&15))<<4));
      acce = __builtin_amdgcn_mfma_f32_16x16x32_bf16(a, bb, acce, 0, 0, 0);
    }
    f32x4 ri4 = *(f32x4*)(smem + 30720 + (i0 + lg*4)*4);
    float* accb = accbo + (size_t)(b & (NCOPY-1)) * 512;
    {
      bf16x4 vb4;
      float vsum = 0.f, vsq = 0.f;
      #pragma unroll
      for (int r = 0; r < 4; ++r){
        float v = accv[r]*ri4[r];
        vb4[r] = (short)f2bf(v); vsum += v; vsq = fmaf(v, v, vsq);
      }
      int ch = g*16 + l15;
      *(bf16x4*)&svout[((size_t)b*256 + ch)*64 + i0 + lg*4] = vb4;
      vsum += __shfl_xor(vsum, 16, 64); vsum += __shfl_xor(vsum, 32, 64);
      vsq  += __shfl_xor(vsq , 16, 64); vsq  += __shfl_xor(vsq , 32, 64);
      if (lg == 0){ atomicAdd(&accb[ch], vsum); atomicAdd(&accb[256+ch], vsq); }
    }
    {
      bf16x4 vb4;
      float vsum = 0.f, vsq = 0.f;
      #pragma unroll
      for (int r = 0; r < 4; ++r){
        float v = acce[r]*ri4[r];
        vb4[r] = (short)f2bf(v); vsum += v; vsq = fmaf(v, v, vsq);
      }
      int ch = 128 + g*16 + l15;
      *(bf16x4*)&svout[((size_t)b*256 + ch)*64 + i0 + lg*4] = vb4;
      vsum += __shfl_xor(vsum, 16, 64); vsum += __shfl_xor(vsum, 32, 64);
      vsq  += __shfl_xor(vsq , 16, 64); vsq  += __shfl_xor(vsq , 32, 64);
      if (lg == 0){ atomicAdd(&accb[ch], vsum); atomicAdd(&accb[256+ch], vsq); }
    }
  }
}

// ---------------------------------------------------------------------------
// bo-BN + pair-sum + transpose (uint-vectorized)
// ---------------------------------------------------------------------------
__global__ __launch_bounds__(256) void k_pairT(const ushort* __restrict__ sv,
    const float* __restrict__ bo, ushort* __restrict__ win)
{
  __shared__ float t[64][66];
  const int c = blockIdx.x, n = blockIdx.y;
  const int tid = threadIdx.x;
  const float s0 = bo[2*c], s1 = bo[2*c+1];
  const float sh = bo[256 + 2*c] + bo[256 + 2*c + 1];
  const ushort* base = sv + (size_t)(n*64)*256*64;
  #pragma unroll
  for (int r = 0; r < 8; ++r){
    int u = tid + r*256;
    int w = u >> 5, hp = u & 31;
    uint a = *(const uint*)&base[((size_t)w*256 + 2*c    )*64 + 2*hp];
    uint bwd = *(const uint*)&base[((size_t)w*256 + 2*c + 1)*64 + 2*hp];
    float a0 = bf2f((ushort)a),   a1 = bf2f((ushort)(a >> 16));
    float b0 = bf2f((ushort)bwd), b1 = bf2f((ushort)(bwd >> 16));
    f32x2 vv;
    vv.x = fmaf(s0, a0, fmaf(s1, b0, sh));
    vv.y = fmaf(s0, a1, fmaf(s1, b1, sh));
    *(f32x2*)&t[w][2*hp] = vv;
  }
  __syncthreads();
  uint* dst = (uint*)(win + (size_t)(n*64)*8192 + (size_t)c*64);
  #pragma unroll
  for (int r = 0; r < 8; ++r){
    int u = tid + r*256;
    int h = u >> 5, wp = u & 31;
    float v0 = t[2*wp    ][h];
    float v1 = t[2*wp + 1][h];
    dst[(size_t)h*4096 + wp] = ((uint)f2bf(v1) << 16) | f2bf(v0);
  }
}

// ---------------------------------------------------------------------------
// bo-BN + pair-sum, no transpose (uint-vectorized)
// ---------------------------------------------------------------------------
__global__ __launch_bounds__(256) void k_pair_w(const ushort* __restrict__ sv,
    const float* __restrict__ bo, ushort* __restrict__ wbuf)
{
  const int m = blockIdx.x, n = blockIdx.y;
  const int tid = threadIdx.x;
  const float s0 = bo[2*m], s1 = bo[2*m+1];
  const float sh = bo[256 + 2*m] + bo[256 + 2*m + 1];
  const uint* p0 = (const uint*)(sv + ((size_t)(n*64)*256 + 2*m    )*64);
  const uint* p1 = (const uint*)(sv + ((size_t)(n*64)*256 + 2*m + 1)*64);
  uint* dst = (uint*)(wbuf + ((size_t)(n*128 + m)*64)*64);
  #pragma unroll
  for (int r = 0; r < 8; ++r){
    int u = tid + r*256;
    int h = u >> 5, wp = u & 31;
    uint a = p0[(size_t)h*8192 + wp];
    uint bwd = p1[(size_t)h*8192 + wp];
    float a0 = bf2f((ushort)a),   a1 = bf2f((ushort)(a >> 16));
    float b0 = bf2f((ushort)bwd), b1 = bf2f((ushort)(bwd >> 16));
    float r0 = fmaf(s0, a0, fmaf(s1, b0, sh));
    float r1 = fmaf(s0, a1, fmaf(s1, b1, sh));
    dst[(size_t)u] = ((uint)f2bf(r1) << 16) | f2bf(r0);
  }
}

// ---------------------------------------------------------------------------

extern "C" void kernel_launch(void* const* d_in, const int* in_sizes, int n_in,
                              void* d_out, int out_size, void* d_ws, size_t ws_size,
                              hipStream_t stream)
{
  const float* x     = (const float*)d_in[0];
  const float* c1_w  = (const float*)d_in[1];
  const float* c1_b  = (const float*)d_in[2];
  const float* cd_w  = (const float*)d_in[3];
  const float* cd_b  = (const float*)d_in[4];
  const float* bn1_g = (const float*)d_in[5];
  const float* bn1_b = (const float*)d_in[6];
  const float* h_qkv = (const float*)d_in[7];
  const float* h_bqg = (const float*)d_in[8];
  const float* h_bqb = (const float*)d_in[9];
  const float* h_bsg = (const float*)d_in[10];
  const float* h_bsb = (const float*)d_in[11];
  const float* h_bog = (const float*)d_in[12];
  const float* h_bob = (const float*)d_in[13];
  const float* h_rel = (const float*)d_in[14];
  const float* w_qkv = (const float*)d_in[15];
  const float* w_bqg = (const float*)d_in[16];
  const float* w_bqb = (const float*)d_in[17];
  const float* w_bsg = (const float*)d_in[18];
  const float* w_bsb = (const float*)d_in[19];
  const float* w_bog = (const float*)d_in[20];
  const float* w_bob = (const float*)d_in[21];
  const float* w_rel = (const float*)d_in[22];
  const float* cu_w  = (const float*)d_in[23];
  const float* cu_b  = (const float*)d_in[24];
  const float* bn2_g = (const float*)d_in[25];
  const float* bn2_b = (const float*)d_in[26];
  float* out = (float*)d_out;
  char* ws = (char*)d_ws;

  // big buffers (aliased across dead stages):
  ushort* OUT0  = (ushort*)(ws + 0);                  // 16MB bf16 (n,128,4096)
  ushort* HIN   = (ushort*)(ws + (32ull<<20));        // 16MB bf16 (1024,128,64)
  float*  QK32H = (float*)(ws + (64ull<<20));         // 32MB fp32 (1024,128,64)
  ushort* VBFH  = (ushort*)(ws + (96ull<<20));        // 16MB bf16 (1024,128,64)
  ushort* SVO   = (ushort*)(ws + 0);                  // 32MB bf16, after OUT0/HIN dead
  ushort* WIN   = (ushort*)(ws + (64ull<<20));        // 16MB bf16, after QK32H dead
  float*  QK32W = (float*)(ws + (96ull<<20));         // 32MB fp32, after VBFH dead
  ushort* VBFW  = (ushort*)(ws + (128ull<<20));       // 16MB bf16
  ushort* WBUF  = (ushort*)(ws + (64ull<<20));        // 16MB bf16, after WIN dead
  ushort* Y2    = (ushort*)(ws + (96ull<<20));        // 32MB bf16, after QK32W dead
  float*  ST    = (float*)(ws + (160ull<<20));        // stats region

  // NCOPY=64 spread accumulators (sizes in floats):
  float* ACC_BN1 = ST;             // 16384
  float* ACC_BQ  = ST + 16384;     // 32768
  float* ACC_SIM = ST + 49152;     // 3072
  float* ACC_BO  = ST + 52224;     // 32768
  float* ACC_BQW = ST + 84992;     // 32768
  float* ACC_SIMW= ST + 117760;    // 3072
  float* ACC_BOW = ST + 120832;    // 32768
  float* ACC_BN2 = ST + 153600;    // 32768  -> ACC total 186368 floats
  float* SCB     = ST + 186368;
  float* SC_BN1 = SCB;        float* SC_BQ  = SCB + 256;
  float* SC_SIM = SCB + 768;  float* SC_BO  = SCB + 816;
  float* SC_BQW = SCB + 1328; float* SC_SIMW= SCB + 1840;
  float* SC_BOW = SCB + 1888; float* SC_BN2 = SCB + 2400;  // -> 2912
  float* RWH  = ST + 189280;  // packed: 5632 floats used (9216 reserved)
  float* RWW  = ST + 198496;  // packed: 5632 floats used
  // bf16 weights (contiguous):
  ushort* CDBF = (ushort*)(ST + 207712);   // 16384
  ushort* QHBF = CDBF + 16384;             // 32768
  ushort* QWBF = CDBF + 49152;             // 32768
  ushort* CUBF = CDBF + 81920;             // 32768
  ushort* C1BF = CDBF + 114688;            // 32768 (end 147456 ushorts)

  hipMemsetAsync(ST, 0, 186368*sizeof(float), stream);

  const dim3 blk(64,4);
  const float inv64k = 1.f/65536.f;
  const float invsim = 1.f/4194304.f;

  // merged weight conversion + packed rel prep
  k_pre<<<580, 256, 0, stream>>>(cd_w, h_qkv, w_qkv, cu_w, c1_w, CDBF,
                                 h_rel, w_rel, RWH, RWW);

  // cd conv + bn1 stats
  k_gemm<128,0,12,0,1><<<1024, 256, 0, stream>>>(x, CDBF, cd_b, OUT0, ACC_BN1, nullptr, nullptr, nullptr);
  k_finalize<<<1, 128, 0, stream>>>(ACC_BN1, bn1_g, bn1_b, SC_BN1, 128, inv64k);
  k_trans_bnrelu<<<dim3(128,16), 256, 0, stream>>>(OUT0, SC_BN1, HIN);

  // ---- h axial ----
  k_gemm<256,3,6,1,0><<<1024, 256, 0, stream>>>(HIN, QHBF, nullptr, QK32H, ACC_BQ, nullptr, nullptr, VBFH);
  k_finalize<<<1, 256, 0, stream>>>(ACC_BQ, h_bqg, h_bqb, SC_BQ, 256, inv64k);
  k_att_stats<<<1024, blk, 0, stream>>>(QK32H, SC_BQ, RWH, ACC_SIM);
  k_finalize<<<1, 32, 0, stream>>>(ACC_SIM, h_bsg, h_bsb, SC_SIM, 24, invsim);
  k_att2<<<dim3(1024,8), blk, 0, stream>>>(QK32H, VBFH, SC_BQ, h_rel, SC_SIM, SVO, ACC_BO);
  k_finalize<<<1, 256, 0, stream>>>(ACC_BO, h_bog, h_bob, SC_BO, 256, inv64k);
  k_pairT<<<dim3(128,16), 256, 0, stream>>>(SVO, SC_BO, WIN);

  // ---- w axial ----
  k_gemm<256,3,6,1,0><<<1024, 256, 0, stream>>>(WIN, QWBF, nullptr, QK32W, ACC_BQW, nullptr, nullptr, VBFW);
  k_finalize<<<1, 256, 0, stream>>>(ACC_BQW, w_bqg, w_bqb, SC_BQW, 256, inv64k);
  k_att_stats<<<1024, blk, 0, stream>>>(QK32W, SC_BQW, RWW, ACC_SIMW);
  k_finalize<<<1, 32, 0, stream>>>(ACC_SIMW, w_bsg, w_bsb, SC_SIMW, 24, invsim);
  k_att2<<<dim3(1024,8), blk, 0, stream>>>(QK32W, VBFW, SC_BQW, w_rel, SC_SIMW, SVO, ACC_BOW);
  k_finalize<<<1, 256, 0, stream>>>(ACC_BOW, w_bog, w_bob, SC_BOW, 256, inv64k);
  k_pair_w<<<dim3(128,16), 256, 0, stream>>>(SVO, SC_BOW, WBUF);

  // cu conv + bn2 stats, then fused residual + c1 conv
  k_gemm<256,0,12,1,1><<<1024, 256, 0, stream>>>(WBUF, CUBF, cu_b, Y2, ACC_BN2, nullptr, nullptr, nullptr);
  k_finalize<<<1, 256, 0, stream>>>(ACC_BN2, bn2_g, bn2_b, SC_BN2, 256, inv64k);
  k_gemm<256,2,12,0,0><<<1024, 256, 0, stream>>>(x, C1BF, c1_b, out, nullptr, Y2, SC_BN2, nullptr);
}